// Round 17
// baseline (84.445 us; speedup 1.0000x reference)
//
#include <hip/hip_runtime.h>
#include <hip/hip_bf16.h>

#define BATCH 4
#define SEQ   4096
#define EMB   1024
#define HS    64

typedef __attribute__((ext_vector_type(4)))  short  short4v;
typedef __attribute__((ext_vector_type(8)))  short  short8v;
typedef __attribute__((ext_vector_type(4)))  float  float4v;
typedef __attribute__((ext_vector_type(16))) float  float16v;
typedef __attribute__((ext_vector_type(8)))  unsigned short ushort8v;
typedef __attribute__((ext_vector_type(2)))  unsigned int uint2v;

// Q pre-scale: 1/sqrt(64) * log2(e) so softmax can use exp2 directly.
#define QSCALE 0.1803368801111204f

static __device__ __forceinline__ unsigned short f2bf(float f){
  __hip_bfloat16 h = __float2bfloat16(f);
  return *reinterpret_cast<unsigned short*>(&h);
}

// pack 2 floats -> 2 bf16 in one dword (round-half-up)
static __device__ __forceinline__ int pk2(float va, float vb){
  unsigned ua = __float_as_uint(va), ub = __float_as_uint(vb);
  return (int)(((ua + 0x8000u) >> 16) | ((ub + 0x8000u) & 0xFFFF0000u));
}

// permlane32_swap: new a = (a_lo, b_lo), new b = (a_hi, b_hi)  (halves = 32-lane rows).
static __device__ __forceinline__ void pl32(int &a, int &b){
#if __has_builtin(__builtin_amdgcn_permlane32_swap)
  uint2v r = __builtin_amdgcn_permlane32_swap((unsigned)a, (unsigned)b, false, false);
  a = (int)r[0]; b = (int)r[1];
#else
  const bool lo_ = ((threadIdx.x & 63) < 32);
  int sa = __shfl_xor(a, 32, 64);
  int sb = __shfl_xor(b, 32, 64);
  int na = lo_ ? a : sb;
  int nb = lo_ ? sa : b;
  a = na; b = nb;
#endif
}

// depth-4 pairwise tree reductions (break the 15/31-deep serial chains)
static __device__ __forceinline__ float vmax16(const float16v &v){
  float a0 = fmaxf(v[0],v[1]),  a1 = fmaxf(v[2],v[3]),  a2 = fmaxf(v[4],v[5]),  a3 = fmaxf(v[6],v[7]);
  float a4 = fmaxf(v[8],v[9]),  a5 = fmaxf(v[10],v[11]),a6 = fmaxf(v[12],v[13]),a7 = fmaxf(v[14],v[15]);
  float b0 = fmaxf(a0,a1), b1 = fmaxf(a2,a3), b2 = fmaxf(a4,a5), b3 = fmaxf(a6,a7);
  return fmaxf(fmaxf(b0,b1), fmaxf(b2,b3));
}
static __device__ __forceinline__ float vsum16(const float16v &v){
  float a0 = v[0]+v[1],  a1 = v[2]+v[3],  a2 = v[4]+v[5],  a3 = v[6]+v[7];
  float a4 = v[8]+v[9],  a5 = v[10]+v[11],a6 = v[12]+v[13],a7 = v[14]+v[15];
  float b0 = a0+a1, b1 = a2+a3, b2 = a4+a5, b3 = a6+a7;
  return (b0+b1) + (b2+b3);
}

// 32x32x16 bf16 (gfx950 full-rate). C/D (HW-verified m74/m101):
//   n = lane&31 (col), m = (reg&3) + 8*(reg>>2) + 4*(lane>>5) (row).
// A: row m=lane&31, k = 8*(lane>>5)+j ; B: col n=lane&31, k = 8*(lane>>5)+j.
static __device__ __forceinline__ float16v mfma32(short8v a, short8v b, float16v c){
#if __has_builtin(__builtin_amdgcn_mfma_f32_32x32x16_bf16)
  return __builtin_amdgcn_mfma_f32_32x32x16_bf16(a, b, c, 0, 0, 0);
#else
  asm("v_mfma_f32_32x32x16_bf16 %0, %1, %2, %0" : "+v"(c) : "v"(a), "v"(b));
  return c;
#endif
}

// ---------------- W pack for 32x32 frags (unchanged) ----------------
__global__ __launch_bounds__(256) void pack32_kernel(
    const float* __restrict__ Wq, const float* __restrict__ Wk, const float* __restrict__ Wv,
    unsigned short* __restrict__ Wpack){
  const int flat = blockIdx.x * 256 + threadIdx.x;   // 0..24575
  const int lane = flat & 63;
  const int f    = flat >> 6;                        // kstep*6 + tile
  const int tile = f % 6;
  const int kstep= f / 6;
  const int k0   = kstep * 16 + (lane >> 5) * 8;
  const int mat  = tile >> 1;
  const int col  = (tile & 1) * 32 + (lane & 31);
  const float* W = (mat == 0) ? Wq : (mat == 1) ? Wk : Wv;
  const float scale = (mat == 0) ? QSCALE : 1.0f;
  short8v pk;
  #pragma unroll
  for (int j = 0; j < 8; ++j) pk[j] = (short)f2bf(W[(size_t)(k0 + j) * HS + col] * scale);
  *reinterpret_cast<short8v*>(Wpack + (size_t)flat * 8) = pk;
}

// ---------------- projection GEMM v5 (round-10 best, verbatim) ----------------
__global__ __launch_bounds__(256) void proj_mfma(
    const float* __restrict__ x, const unsigned short* __restrict__ Wpack,
    unsigned short* __restrict__ Qb, unsigned short* __restrict__ Kb,
    unsigned short* __restrict__ Vt){
  __shared__ __align__(16) char lds[50688];     // staging 2x16KB; Red[64][198] fp32 in epilogue
  const int tid  = threadIdx.x;
  const int lane = tid & 63;
  const int w    = tid >> 6;
  const int wq   = w & 1;                       // row strip (32 rows)
  const int wc   = w >> 1;                      // col half (3 tiles)
  const int l31  = lane & 31;
  const int lh   = lane >> 5;
  const int grow0 = blockIdx.x * 64;

  float16v acc0 = {0,0,0,0,0,0,0,0,0,0,0,0,0,0,0,0};
  float16v acc1 = {0,0,0,0,0,0,0,0,0,0,0,0,0,0,0,0};
  float16v acc2 = {0,0,0,0,0,0,0,0,0,0,0,0,0,0,0,0};

  #define STAGE(BUFB, KT) do { \
    _Pragma("unroll") \
    for (int i2 = 0; i2 < 4; ++i2){ \
      const int rr = i2 * 16 + (tid >> 4); \
      const int cbyte = (tid & 15) * 16; \
      const char* gsrc = (const char*)x + (((size_t)(grow0 + rr)) << 12) + ((size_t)(KT) << 8) \
                         + (cbyte ^ ((rr & 15) << 4)); \
      __builtin_amdgcn_global_load_lds( \
          (const __attribute__((address_space(1))) unsigned int*)gsrc, \
          (__attribute__((address_space(3))) unsigned int*)(lds + (BUFB) + i2 * 4096 + tid * 16), \
          16, 0, 0); \
    } } while(0)

  const unsigned short* wpl = Wpack + (size_t)lane * 8;
  const int rb = (wq * 32 + l31) * 256;         // row byte base in tile
  const int sw = (l31 & 15) << 4;               // XOR swizzle ((row&15)<<4)
  int cur = 0;

  STAGE(0, 0);
  __syncthreads();

  for (int kt = 0; kt < 16; ++kt){
    short8v bf[12];
    #pragma unroll
    for (int ks4 = 0; ks4 < 4; ++ks4)
      #pragma unroll
      for (int tt = 0; tt < 3; ++tt)
        bf[ks4 * 3 + tt] = *reinterpret_cast<const short8v*>(
            wpl + (size_t)((kt * 4 + ks4) * 6 + wc * 3 + tt) * 512);
    __builtin_amdgcn_sched_barrier(0);
    if (kt < 15) STAGE((cur ^ 1) * 16384, kt + 1);
    __builtin_amdgcn_sched_barrier(0);
    const int bufb = cur * 16384;
    #pragma unroll
    for (int ks4 = 0; ks4 < 4; ++ks4){
      const int cb = ks4 * 64 + lh * 32;
      float4 a0 = *reinterpret_cast<const float4*>(lds + bufb + rb + ((cb     ) ^ sw));
      float4 a1 = *reinterpret_cast<const float4*>(lds + bufb + rb + ((cb + 16) ^ sw));
      short8v af;
      af[0] = (short)f2bf(a0.x); af[1] = (short)f2bf(a0.y);
      af[2] = (short)f2bf(a0.z); af[3] = (short)f2bf(a0.w);
      af[4] = (short)f2bf(a1.x); af[5] = (short)f2bf(a1.y);
      af[6] = (short)f2bf(a1.z); af[7] = (short)f2bf(a1.w);
      acc0 = mfma32(af, bf[ks4 * 3 + 0], acc0);
      acc1 = mfma32(af, bf[ks4 * 3 + 1], acc1);
      acc2 = mfma32(af, bf[ks4 * 3 + 2], acc2);
    }
    __syncthreads();
    cur ^= 1;
  }
  #undef STAGE

  float* Red = reinterpret_cast<float*>(lds);
  {
    const int colb  = wc * 96 + l31;
    const int rbase = wq * 32 + 4 * lh;
    #pragma unroll
    for (int reg = 0; reg < 16; ++reg){
      const int row = rbase + (reg & 3) + 8 * (reg >> 2);
      Red[row * 198 + colb     ] = acc0[reg];
      Red[row * 198 + colb + 32] = acc1[reg];
      Red[row * 198 + colb + 64] = acc2[reg];
    }
  }
  __syncthreads();
  #pragma unroll
  for (int i = 0; i < 4; ++i){
    const int flat = tid + i * 256;             // 0..1023
    const int row  = flat >> 4;                 // 0..63
    const int c16  = flat & 15;                 // 8-col chunk
    ushort8v pk;
    #pragma unroll
    for (int j = 0; j < 8; ++j) pk[j] = f2bf(Red[row * 198 + c16 * 8 + j]);
    unsigned short* dst = (c16 < 8) ? (Qb + (size_t)(grow0 + row) * HS + c16 * 8)
                                    : (Kb + (size_t)(grow0 + row) * HS + (c16 - 8) * 8);
    *reinterpret_cast<ushort8v*>(dst) = pk;
  }
  #pragma unroll
  for (int i = 0; i < 4; ++i){
    const int flat = tid + i * 256;
    const int vcol = flat >> 4;                 // 0..63
    const int rg   = flat & 15;                 // 4-row group
    short4v pk;
    #pragma unroll
    for (int j = 0; j < 4; ++j) pk[j] = (short)f2bf(Red[(rg * 4 + j) * 198 + 128 + vcol]);
    *reinterpret_cast<short4v*>(Vt + (size_t)vcol * (BATCH * SEQ) + grow0 + rg * 4) = pk;
  }
}

// ---------------- flash attention partials v8: 8-wave blocks, QB=256 ----------------
// Block: 512 thr = 8 waves; wave wq owns 32 q-rows; block q-span = 256 (QB).
// K/V^T double-buffered via global_load_lds (1+1 insts/thread/tile); 1 barrier/tile.
// Inner tile body = v6b (proven) + tree reductions. LDS amortized over 8 waves.
template<int CHUNK>
__global__ __launch_bounds__(512, 4) void attn_partial(
    const unsigned short* __restrict__ Qb, const unsigned short* __restrict__ Kb,
    const unsigned short* __restrict__ Vt,
    unsigned short* __restrict__ Opart, float* __restrict__ Mpart, float* __restrict__ Lpart){
  constexpr int QB  = 256;
  constexpr int GS  = CHUNK / QB;
  constexpr int NG  = SEQ / CHUNK;
  constexpr int PCB = GS * NG * (NG + 1) / 2;
  constexpr int NBS = BATCH * SEQ;

  __shared__ __align__(16) unsigned short Ks[2 * 64 * 64];   // 16 KB
  __shared__ __align__(16) unsigned short Vs[2 * 64 * 64];   // 16 KB

  const int b = blockIdx.x / PCB;
  const int g = blockIdx.x % PCB;
  int a = 0, accb = 0;
  while (g >= accb + GS * (a + 1)) { accb += GS * (a + 1); ++a; }
  const int rem = g - accb;
  const int qj  = a * GS + rem / (a + 1);          // 256-row q-block
  const int c   = rem % (a + 1);                   // key chunk

  const int tid  = threadIdx.x;
  const int lane = tid & 63;
  const int wq   = tid >> 6;                       // wave 0..7 -> q-strip
  const int l31  = lane & 31;
  const int lh   = lane >> 5;

  const size_t bbase = (size_t)b * SEQ * HS;
  const int qb0    = qj * QB + wq * 32;
  const int gq     = qb0 + l31;
  const int cstart = c * CHUNK;
  const int kend   = min(cstart + CHUNK, qj * QB + QB);
  const int ntile  = (kend - cstart) >> 6;

  char* KsB = reinterpret_cast<char*>(Ks);
  char* VsB = reinterpret_cast<char*>(Vs);

  // stage tile T into buffer BSEL: 1 K-load + 1 V-load per thread (512 thr x 16B = 8KB each)
  #define AT_STAGE(T, BSEL) do { \
    const int rr = tid >> 3; \
    const int cb = ((tid & 7) * 16) ^ ((rr & 7) << 4); \
    const char* kg = (const char*)(Kb + bbase + (size_t)(cstart + (T) * 64 + rr) * HS) + cb; \
    __builtin_amdgcn_global_load_lds( \
        (const __attribute__((address_space(1))) unsigned int*)kg, \
        (__attribute__((address_space(3))) unsigned int*)(KsB + (BSEL) + tid * 16), 16, 0, 0); \
    const char* vg = (const char*)(Vt + (size_t)rr * NBS + b * SEQ + cstart + (T) * 64) + cb; \
    __builtin_amdgcn_global_load_lds( \
        (const __attribute__((address_space(1))) unsigned int*)vg, \
        (__attribute__((address_space(3))) unsigned int*)(VsB + (BSEL) + tid * 16), 16, 0, 0); \
  } while(0)

  short8v qf[4];
  #pragma unroll
  for (int ds = 0; ds < 4; ++ds)
    qf[ds] = *reinterpret_cast<const short8v*>(Qb + bbase + (size_t)(qb0 + l31) * HS + ds * 16 + 8 * lh);

  float m = -1e30f, lsum = 0.f;
  float16v o0 = {0,0,0,0,0,0,0,0,0,0,0,0,0,0,0,0};
  float16v o1 = {0,0,0,0,0,0,0,0,0,0,0,0,0,0,0,0};

  AT_STAGE(0, 0);
  __syncthreads();

  for (int t = 0; t < ntile; ++t){
    const int bsel = (t & 1) * 8192;
    if (t + 1 < ntile) AT_STAGE(t + 1, bsel ^ 8192);   // in flight across compute

    const int k0 = cstart + t * 64;
    if (k0 <= qb0 + 31){
      const float16v z16 = {0,0,0,0,0,0,0,0,0,0,0,0,0,0,0,0};
      float16v st0 = z16, st1;
      #pragma unroll
      for (int ds = 0; ds < 4; ++ds){
        const int byte0 = bsel + ((l31 * 128 + ds * 32 + lh * 16) ^ ((l31 & 7) << 4));
        st0 = mfma32(*reinterpret_cast<const short8v*>(KsB + byte0), qf[ds], st0);
      }
      const bool do1 = (k0 + 32 <= qb0 + 31);
      if (do1){
        st1 = z16;
        #pragma unroll
        for (int ds = 0; ds < 4; ++ds){
          const int byte1 = bsel + (((32 + l31) * 128 + ds * 32 + lh * 16) ^ ((l31 & 7) << 4));
          st1 = mfma32(*reinterpret_cast<const short8v*>(KsB + byte1), qf[ds], st1);
        }
      }
      // ---- causal mask ----
      if (k0 + 31 > qb0){
        #pragma unroll
        for (int r = 0; r < 16; ++r){
          const int key = k0 + (r & 3) + 8 * (r >> 2) + 4 * lh;
          if (key > gq) st0[r] = -1e30f;
        }
      }
      if (do1 && (k0 + 63 > qb0)){
        #pragma unroll
        for (int r = 0; r < 16; ++r){
          const int key = k0 + 32 + (r & 3) + 8 * (r >> 2) + 4 * lh;
          if (key > gq) st1[r] = -1e30f;
        }
      }
      // ---- online softmax: tree reduce + permlane32_swap ----
      float pmax = vmax16(st0);
      if (do1) pmax = fmaxf(pmax, vmax16(st1));
      {
        int pa = __float_as_int(pmax), pb = __float_as_int(pmax);
        pl32(pa, pb);
        pmax = fmaxf(__int_as_float(pa), __int_as_float(pb));
      }
      // T13 defer-max
      if (!__all(pmax - m <= 8.0f)){
        const float mnew = fmaxf(m, pmax);
        const float corr = exp2f(m - mnew);
        lsum *= corr;
        #pragma unroll
        for (int r = 0; r < 16; ++r){ o0[r] *= corr; o1[r] *= corr; }
        m = mnew;
      }
      #pragma unroll
      for (int r = 0; r < 16; ++r) st0[r] = exp2f(st0[r] - m);
      float ps = vsum16(st0);
      if (do1){
        #pragma unroll
        for (int r = 0; r < 16; ++r) st1[r] = exp2f(st1[r] - m);
        ps += vsum16(st1);
      }
      {
        int pa = __float_as_int(ps), pb = __float_as_int(ps);
        pl32(pa, pb);
        ps = __int_as_float(pa) + __int_as_float(pb);
      }
      lsum += ps;

      // ---- P^T B-frags: pk2 + permlane32_swap ----
      short8v pf[4];
      #define MAKE_PF(ST, BASE, OUT) { \
        int aa = pk2(ST[BASE+0], ST[BASE+1]); \
        int cc2 = pk2(ST[BASE+2], ST[BASE+3]); \
        int bb = pk2(ST[BASE+4], ST[BASE+5]); \
        int dd = pk2(ST[BASE+6], ST[BASE+7]); \
        pl32(aa, bb); pl32(cc2, dd); \
        int4 wi; wi.x = aa; wi.y = cc2; wi.z = bb; wi.w = dd; \
        OUT = *reinterpret_cast<short8v*>(&wi); }
      MAKE_PF(st0, 0, pf[0])
      MAKE_PF(st0, 8, pf[1])
      if (do1){
        MAKE_PF(st1, 0, pf[2])
        MAKE_PF(st1, 8, pf[3])
      }
      #undef MAKE_PF

      // ---- O^T += V^T * P^T ----
      #pragma unroll
      for (int s = 0; s < 2; ++s){
        const int byteA = bsel + ((l31 * 128 + s * 32 + lh * 16) ^ ((l31 & 7) << 4));
        const int byteB = bsel + (((32 + l31) * 128 + s * 32 + lh * 16) ^ ((l31 & 7) << 4));
        o0 = mfma32(*reinterpret_cast<const short8v*>(VsB + byteA), pf[s], o0);
        o1 = mfma32(*reinterpret_cast<const short8v*>(VsB + byteB), pf[s], o1);
      }
      if (do1){
        #pragma unroll
        for (int s = 2; s < 4; ++s){
          const int byteA = bsel + ((l31 * 128 + s * 32 + lh * 16) ^ ((l31 & 7) << 4));
          const int byteB = bsel + (((32 + l31) * 128 + s * 32 + lh * 16) ^ ((l31 & 7) << 4));
          o0 = mfma32(*reinterpret_cast<const short8v*>(VsB + byteA), pf[s], o0);
          o1 = mfma32(*reinterpret_cast<const short8v*>(VsB + byteB), pf[s], o1);
        }
      }
    }
    __syncthreads();   // drains stage(t+1) + releases buf t&1
  }
  #undef AT_STAGE

  const int prow = (b * PCB + g) * QB + wq * 32 + l31;
  unsigned short* Od = Opart + (size_t)prow * 64;
  #define WRITE_O(OO, DT) { \
    _Pragma("unroll") \
    for (int quad = 0; quad < 4; ++quad){ \
      short4v pkk; \
      _Pragma("unroll") \
      for (int r = 0; r < 4; ++r) pkk[r] = (short)f2bf(OO[quad * 4 + r]); \
      *reinterpret_cast<short4v*>(Od + DT * 32 + 8 * quad + 4 * lh) = pkk; } }
  WRITE_O(o0, 0)
  WRITE_O(o1, 1)
  #undef WRITE_O
  if (lane < 32){
    Mpart[prow] = m;
    Lpart[prow] = lsum;
  }
}

// ---------------- combine partials (QB=256) ----------------
template<int CHUNK>
__global__ __launch_bounds__(256) void combine_kernel(
    const unsigned short* __restrict__ Opart, const float* __restrict__ Mpart,
    const float* __restrict__ Lpart, float* __restrict__ out){
  constexpr int QB  = 256;
  constexpr int GS  = CHUNK / QB;
  constexpr int NG  = SEQ / CHUNK;
  constexpr int PCB = GS * NG * (NG + 1) / 2;
  const int gid = blockIdx.x * 4 + (threadIdx.x >> 6);   // global row 0..16383
  const int d   = threadIdx.x & 63;
  const int b   = gid >> 12;
  const int q   = gid & (SEQ - 1);
  const int qj  = q >> 8;                                // 256-row q-block
  const int A   = qj / GS;
  const int nch = A + 1;
  const int p0  = b * PCB + GS * A * (A + 1) / 2 + (qj - A * GS) * (A + 1);
  const int ql  = q & (QB - 1);

  float M = -1e30f;
  for (int cc = 0; cc < nch; ++cc) M = fmaxf(M, Mpart[(p0 + cc) * QB + ql]);
  float L = 0.f, O = 0.f;
  for (int cc = 0; cc < nch; ++cc){
    const float s = exp2f(Mpart[(p0 + cc) * QB + ql] - M);
    L += s * Lpart[(p0 + cc) * QB + ql];
    const unsigned short ob = Opart[((size_t)(p0 + cc) * QB + ql) * 64 + d];
    O += s * __uint_as_float((unsigned)ob << 16);
  }
  out[(size_t)gid * 64 + d] = O / L;
}

extern "C" void kernel_launch(void* const* d_in, const int* in_sizes, int n_in,
                              void* d_out, int out_size, void* d_ws, size_t ws_size,
                              hipStream_t stream){
  const float* x  = (const float*)d_in[0];
  const float* Wq = (const float*)d_in[1];
  const float* Wk = (const float*)d_in[2];
  const float* Wv = (const float*)d_in[3];

  const size_t nqkv = (size_t)BATCH * SEQ * HS;
  unsigned short* Qb = (unsigned short*)d_ws;
  unsigned short* Kb = Qb + nqkv;
  unsigned short* Vt = Kb + nqkv;                     // [HS][BATCH*SEQ]
  unsigned short* Wpack = Vt + nqkv;                  // 196608 ushorts = 384 KB
  unsigned short* Opart = Wpack + (size_t)196608;

  pack32_kernel<<<96, 256, 0, stream>>>(Wq, Wk, Wv, Wpack);
  proj_mfma<<<(BATCH * SEQ) / 64, 256, 0, stream>>>(x, Wpack, Qb, Kb, Vt);

  // QB=256 partial counts: PCB = GS*NG*(NG+1)/2
  constexpr int PCB256  = 1 * 16 * 17 / 2;    // 136  (CHUNK=256: ntile==4 uniform)
  constexpr int PCB512  = 2 * 8 * 9 / 2;      // 72
  constexpr int PCB4096 = 16 * 1 * 2 / 2;     // 16
  const size_t base_bytes = (3 * nqkv + (size_t)196608) * sizeof(unsigned short);
  auto pbytes = [](int pcb){ return (size_t)BATCH * pcb * 256 * (64 * 2 + 8); };

  if (ws_size >= base_bytes + pbytes(PCB256)){
    float* Mpart = (float*)(Opart + (size_t)BATCH * PCB256 * 256 * 64);
    float* Lpart = Mpart + (size_t)BATCH * PCB256 * 256;
    attn_partial<256><<<BATCH * PCB256, 512, 0, stream>>>(Qb, Kb, Vt, Opart, Mpart, Lpart);
    combine_kernel<256><<<BATCH * SEQ / 4, 256, 0, stream>>>(Opart, Mpart, Lpart, (float*)d_out);
  } else if (ws_size >= base_bytes + pbytes(PCB512)){
    float* Mpart = (float*)(Opart + (size_t)BATCH * PCB512 * 256 * 64);
    float* Lpart = Mpart + (size_t)BATCH * PCB512 * 256;
    attn_partial<512><<<BATCH * PCB512, 512, 0, stream>>>(Qb, Kb, Vt, Opart, Mpart, Lpart);
    combine_kernel<512><<<BATCH * SEQ / 4, 256, 0, stream>>>(Opart, Mpart, Lpart, (float*)d_out);
  } else {
    float* Mpart = (float*)(Opart + (size_t)BATCH * PCB4096 * 256 * 64);
    float* Lpart = Mpart + (size_t)BATCH * PCB4096 * 256;
    attn_partial<4096><<<BATCH * PCB4096, 512, 0, stream>>>(Qb, Kb, Vt, Opart, Mpart, Lpart);
    combine_kernel<4096><<<BATCH * SEQ / 4, 256, 0, stream>>>(Opart, Mpart, Lpart, (float*)d_out);
  }
}

// Round 18
// 72.856 us; speedup vs baseline: 1.1591x; 1.1591x over previous
//
#include <hip/hip_runtime.h>
#include <hip/hip_bf16.h>

#define BATCH 4
#define SEQ   4096
#define EMB   1024
#define HS    64

typedef __attribute__((ext_vector_type(4)))  short  short4v;
typedef __attribute__((ext_vector_type(8)))  short  short8v;
typedef __attribute__((ext_vector_type(4)))  float  float4v;
typedef __attribute__((ext_vector_type(16))) float  float16v;
typedef __attribute__((ext_vector_type(8)))  unsigned short ushort8v;
typedef __attribute__((ext_vector_type(2)))  unsigned int uint2v;

// Q pre-scale: 1/sqrt(64) * log2(e) so softmax can use exp2 directly.
#define QSCALE 0.1803368801111204f

static __device__ __forceinline__ unsigned short f2bf(float f){
  __hip_bfloat16 h = __float2bfloat16(f);
  return *reinterpret_cast<unsigned short*>(&h);
}

// pack 2 floats -> 2 bf16 in one dword (round-half-up)
static __device__ __forceinline__ int pk2(float va, float vb){
  unsigned ua = __float_as_uint(va), ub = __float_as_uint(vb);
  return (int)(((ua + 0x8000u) >> 16) | ((ub + 0x8000u) & 0xFFFF0000u));
}

// permlane32_swap: new a = (a_lo, b_lo), new b = (a_hi, b_hi)  (halves = 32-lane rows).
static __device__ __forceinline__ void pl32(int &a, int &b){
#if __has_builtin(__builtin_amdgcn_permlane32_swap)
  uint2v r = __builtin_amdgcn_permlane32_swap((unsigned)a, (unsigned)b, false, false);
  a = (int)r[0]; b = (int)r[1];
#else
  const bool lo_ = ((threadIdx.x & 63) < 32);
  int sa = __shfl_xor(a, 32, 64);
  int sb = __shfl_xor(b, 32, 64);
  int na = lo_ ? a : sb;
  int nb = lo_ ? sa : b;
  a = na; b = nb;
#endif
}

// 32x32x16 bf16 (gfx950 full-rate). C/D (HW-verified m74/m101):
//   n = lane&31 (col), m = (reg&3) + 8*(reg>>2) + 4*(lane>>5) (row).
// A: row m=lane&31, k = 8*(lane>>5)+j ; B: col n=lane&31, k = 8*(lane>>5)+j.
static __device__ __forceinline__ float16v mfma32(short8v a, short8v b, float16v c){
#if __has_builtin(__builtin_amdgcn_mfma_f32_32x32x16_bf16)
  return __builtin_amdgcn_mfma_f32_32x32x16_bf16(a, b, c, 0, 0, 0);
#else
  asm("v_mfma_f32_32x32x16_bf16 %0, %1, %2, %0" : "+v"(c) : "v"(a), "v"(b));
  return c;
#endif
}

// ---------------- W pack for 32x32 frags (unchanged) ----------------
__global__ __launch_bounds__(256) void pack32_kernel(
    const float* __restrict__ Wq, const float* __restrict__ Wk, const float* __restrict__ Wv,
    unsigned short* __restrict__ Wpack){
  const int flat = blockIdx.x * 256 + threadIdx.x;   // 0..24575
  const int lane = flat & 63;
  const int f    = flat >> 6;                        // kstep*6 + tile
  const int tile = f % 6;
  const int kstep= f / 6;
  const int k0   = kstep * 16 + (lane >> 5) * 8;
  const int mat  = tile >> 1;
  const int col  = (tile & 1) * 32 + (lane & 31);
  const float* W = (mat == 0) ? Wq : (mat == 1) ? Wk : Wv;
  const float scale = (mat == 0) ? QSCALE : 1.0f;
  short8v pk;
  #pragma unroll
  for (int j = 0; j < 8; ++j) pk[j] = (short)f2bf(W[(size_t)(k0 + j) * HS + col] * scale);
  *reinterpret_cast<short8v*>(Wpack + (size_t)flat * 8) = pk;
}

// ---------------- projection GEMM v5.5: v5 schedule, 512 blocks x 128 thr ----------------
// Block 128 thr = 2 waves (col halves); 32 rows x 192 cols; BK=64 x 16 iters.
// Per iteration: [B-frag loads] -> SBAR -> [STAGE next x-tile] -> SBAR -> [MFMA] -> sync.
// 2 blocks/CU: the per-barrier stage-drain exposure of one block overlaps the other's compute.
__global__ __launch_bounds__(128) void proj_mfma(
    const float* __restrict__ x, const unsigned short* __restrict__ Wpack,
    unsigned short* __restrict__ Qb, unsigned short* __restrict__ Kb,
    unsigned short* __restrict__ Vt){
  __shared__ __align__(16) char lds[25344];     // staging 2x8KB; Red[32][198] fp32 in epilogue
  const int tid  = threadIdx.x;
  const int lane = tid & 63;
  const int wc   = tid >> 6;                    // wave 0/1 -> col half (3 tiles)
  const int l31  = lane & 31;
  const int lh   = lane >> 5;
  const int grow0 = blockIdx.x * 32;

  float16v acc0 = {0,0,0,0,0,0,0,0,0,0,0,0,0,0,0,0};
  float16v acc1 = {0,0,0,0,0,0,0,0,0,0,0,0,0,0,0,0};
  float16v acc2 = {0,0,0,0,0,0,0,0,0,0,0,0,0,0,0,0};

  // stage one 32x256B x-tile: 4 insts x 128 thr x 16B; LDS linear, source pre-swizzled
  #define STAGE(BUFB, KT) do { \
    _Pragma("unroll") \
    for (int i2 = 0; i2 < 4; ++i2){ \
      const int rr = i2 * 8 + (tid >> 4); \
      const int cbyte = (tid & 15) * 16; \
      const char* gsrc = (const char*)x + (((size_t)(grow0 + rr)) << 12) + ((size_t)(KT) << 8) \
                         + (cbyte ^ ((rr & 15) << 4)); \
      __builtin_amdgcn_global_load_lds( \
          (const __attribute__((address_space(1))) unsigned int*)gsrc, \
          (__attribute__((address_space(3))) unsigned int*)(lds + (BUFB) + i2 * 2048 + tid * 16), \
          16, 0, 0); \
    } } while(0)

  const unsigned short* wpl = Wpack + (size_t)lane * 8;
  const int rb = l31 * 256;                     // row byte base in tile
  const int sw = (l31 & 15) << 4;               // XOR swizzle ((row&15)<<4)
  int cur = 0;

  STAGE(0, 0);
  __syncthreads();

  for (int kt = 0; kt < 16; ++kt){
    // (1) B-fragment loads for this iteration -- ISSUED FIRST (in-order vmcnt!)
    short8v bf[12];
    #pragma unroll
    for (int ks4 = 0; ks4 < 4; ++ks4)
      #pragma unroll
      for (int tt = 0; tt < 3; ++tt)
        bf[ks4 * 3 + tt] = *reinterpret_cast<const short8v*>(
            wpl + (size_t)((kt * 4 + ks4) * 6 + wc * 3 + tt) * 512);
    __builtin_amdgcn_sched_barrier(0);
    // (2) stage next x-tile (stays in flight across the compute below)
    if (kt < 15) STAGE((cur ^ 1) * 8192, kt + 1);
    __builtin_amdgcn_sched_barrier(0);
    // (3) compute from LDS buf cur + B regs
    const int bufb = cur * 8192;
    #pragma unroll
    for (int ks4 = 0; ks4 < 4; ++ks4){
      const int cb = ks4 * 64 + lh * 32;
      float4 a0 = *reinterpret_cast<const float4*>(lds + bufb + rb + ((cb     ) ^ sw));
      float4 a1 = *reinterpret_cast<const float4*>(lds + bufb + rb + ((cb + 16) ^ sw));
      short8v af;
      af[0] = (short)f2bf(a0.x); af[1] = (short)f2bf(a0.y);
      af[2] = (short)f2bf(a0.z); af[3] = (short)f2bf(a0.w);
      af[4] = (short)f2bf(a1.x); af[5] = (short)f2bf(a1.y);
      af[6] = (short)f2bf(a1.z); af[7] = (short)f2bf(a1.w);
      acc0 = mfma32(af, bf[ks4 * 3 + 0], acc0);
      acc1 = mfma32(af, bf[ks4 * 3 + 1], acc1);
      acc2 = mfma32(af, bf[ks4 * 3 + 2], acc2);
    }
    __syncthreads();                            // drains stage at iteration end only
    cur ^= 1;
  }
  #undef STAGE

  // ---- epilogue: bounce C through LDS (Red[32][198] fp32 = 25.3 KB) ----
  float* Red = reinterpret_cast<float*>(lds);
  {
    const int colb  = wc * 96 + l31;
    const int rbase = 4 * lh;
    #pragma unroll
    for (int reg = 0; reg < 16; ++reg){
      const int row = rbase + (reg & 3) + 8 * (reg >> 2);
      Red[row * 198 + colb     ] = acc0[reg];
      Red[row * 198 + colb + 32] = acc1[reg];
      Red[row * 198 + colb + 64] = acc2[reg];
    }
  }
  __syncthreads();
  // cols 0..63 -> Q, 64..127 -> K (row-major bf16)
  #pragma unroll
  for (int i = 0; i < 4; ++i){
    const int flat = tid + i * 128;             // 0..511
    const int row  = flat >> 4;                 // 0..31
    const int c16  = flat & 15;                 // 8-col chunk
    ushort8v pk;
    #pragma unroll
    for (int j = 0; j < 8; ++j) pk[j] = f2bf(Red[row * 198 + c16 * 8 + j]);
    unsigned short* dst = (c16 < 8) ? (Qb + (size_t)(grow0 + row) * HS + c16 * 8)
                                    : (Kb + (size_t)(grow0 + row) * HS + (c16 - 8) * 8);
    *reinterpret_cast<ushort8v*>(dst) = pk;
  }
  // cols 128..191 -> V transposed
  #pragma unroll
  for (int i = 0; i < 4; ++i){
    const int flat = tid + i * 128;
    const int vcol = flat >> 3;                 // 0..63
    const int rg   = flat & 7;                  // 4-row group (rows rg*4..rg*4+3)
    short4v pk;
    #pragma unroll
    for (int j = 0; j < 4; ++j) pk[j] = (short)f2bf(Red[(rg * 4 + j) * 198 + 128 + vcol]);
    *reinterpret_cast<short4v*>(Vt + (size_t)vcol * (BATCH * SEQ) + grow0 + rg * 4) = pk;
  }
}

// ---------------- flash attention partials v6b (round-15 best, verbatim) ----------------
template<int CHUNK>
__global__ __launch_bounds__(256, 4) void attn_partial(
    const unsigned short* __restrict__ Qb, const unsigned short* __restrict__ Kb,
    const unsigned short* __restrict__ Vt,
    unsigned short* __restrict__ Opart, float* __restrict__ Mpart, float* __restrict__ Lpart){
  constexpr int QB  = 128;
  constexpr int GS  = CHUNK / QB;
  constexpr int NG  = SEQ / CHUNK;
  constexpr int PCB = GS * NG * (NG + 1) / 2;
  constexpr int NBS = BATCH * SEQ;

  __shared__ __align__(16) unsigned short Ks[2 * 64 * 64];   // 16 KB
  __shared__ __align__(16) unsigned short Vs[2 * 64 * 64];   // 16 KB

  const int b = blockIdx.x / PCB;
  const int g = blockIdx.x % PCB;
  int a = 0, accb = 0;
  while (g >= accb + GS * (a + 1)) { accb += GS * (a + 1); ++a; }
  const int rem = g - accb;
  const int qj  = a * GS + rem / (a + 1);          // 128-row q-block
  const int c   = rem % (a + 1);                   // key chunk

  const int tid  = threadIdx.x;
  const int lane = tid & 63;
  const int wq   = tid >> 6;                       // wave 0..3 -> q-strip
  const int l31  = lane & 31;
  const int lh   = lane >> 5;

  const size_t bbase = (size_t)b * SEQ * HS;
  const int qb0    = qj * QB + wq * 32;
  const int gq     = qb0 + l31;
  const int cstart = c * CHUNK;
  const int kend   = min(cstart + CHUNK, qj * QB + QB);
  const int ntile  = (kend - cstart) >> 6;

  char* KsB = reinterpret_cast<char*>(Ks);
  char* VsB = reinterpret_cast<char*>(Vs);

  #define AT_STAGE(T, BSEL) do { \
    _Pragma("unroll") \
    for (int i2 = 0; i2 < 2; ++i2){ \
      const int rr = (tid >> 3) + i2 * 32; \
      const int cb = ((tid & 7) * 16) ^ ((rr & 7) << 4); \
      const char* kg = (const char*)(Kb + bbase + (size_t)(cstart + (T) * 64 + rr) * HS) + cb; \
      __builtin_amdgcn_global_load_lds( \
          (const __attribute__((address_space(1))) unsigned int*)kg, \
          (__attribute__((address_space(3))) unsigned int*)(KsB + (BSEL) + i2 * 4096 + tid * 16), 16, 0, 0); \
      const char* vg = (const char*)(Vt + (size_t)rr * NBS + b * SEQ + cstart + (T) * 64) + cb; \
      __builtin_amdgcn_global_load_lds( \
          (const __attribute__((address_space(1))) unsigned int*)vg, \
          (__attribute__((address_space(3))) unsigned int*)(VsB + (BSEL) + i2 * 4096 + tid * 16), 16, 0, 0); \
    } } while(0)

  short8v qf[4];
  #pragma unroll
  for (int ds = 0; ds < 4; ++ds)
    qf[ds] = *reinterpret_cast<const short8v*>(Qb + bbase + (size_t)(qb0 + l31) * HS + ds * 16 + 8 * lh);

  float m = -1e30f, lsum = 0.f;
  float16v o0 = {0,0,0,0,0,0,0,0,0,0,0,0,0,0,0,0};
  float16v o1 = {0,0,0,0,0,0,0,0,0,0,0,0,0,0,0,0};

  AT_STAGE(0, 0);
  __syncthreads();

  for (int t = 0; t < ntile; ++t){
    const int bsel = (t & 1) * 8192;
    if (t + 1 < ntile) AT_STAGE(t + 1, bsel ^ 8192);   // in flight across compute

    const int k0 = cstart + t * 64;
    if (k0 <= qb0 + 31){
      const float16v z16 = {0,0,0,0,0,0,0,0,0,0,0,0,0,0,0,0};
      float16v st0 = z16, st1;
      #pragma unroll
      for (int ds = 0; ds < 4; ++ds){
        const int byte0 = bsel + ((l31 * 128 + ds * 32 + lh * 16) ^ ((l31 & 7) << 4));
        st0 = mfma32(*reinterpret_cast<const short8v*>(KsB + byte0), qf[ds], st0);
      }
      const bool do1 = (k0 + 32 <= qb0 + 31);
      if (do1){
        st1 = z16;
        #pragma unroll
        for (int ds = 0; ds < 4; ++ds){
          const int byte1 = bsel + (((32 + l31) * 128 + ds * 32 + lh * 16) ^ ((l31 & 7) << 4));
          st1 = mfma32(*reinterpret_cast<const short8v*>(KsB + byte1), qf[ds], st1);
        }
      }
      // ---- causal mask ----
      if (k0 + 31 > qb0){
        #pragma unroll
        for (int r = 0; r < 16; ++r){
          const int key = k0 + (r & 3) + 8 * (r >> 2) + 4 * lh;
          if (key > gq) st0[r] = -1e30f;
        }
      }
      if (do1 && (k0 + 63 > qb0)){
        #pragma unroll
        for (int r = 0; r < 16; ++r){
          const int key = k0 + 32 + (r & 3) + 8 * (r >> 2) + 4 * lh;
          if (key > gq) st1[r] = -1e30f;
        }
      }
      // ---- online softmax; cross-lane via permlane32_swap ----
      float pmax = st0[0];
      #pragma unroll
      for (int r = 1; r < 16; ++r) pmax = fmaxf(pmax, st0[r]);
      if (do1)
        #pragma unroll
        for (int r = 0; r < 16; ++r) pmax = fmaxf(pmax, st1[r]);
      {
        int pa = __float_as_int(pmax), pb = __float_as_int(pmax);
        pl32(pa, pb);
        pmax = fmaxf(__int_as_float(pa), __int_as_float(pb));
      }
      // T13 defer-max
      if (!__all(pmax - m <= 8.0f)){
        const float mnew = fmaxf(m, pmax);
        const float corr = exp2f(m - mnew);
        lsum *= corr;
        #pragma unroll
        for (int r = 0; r < 16; ++r){ o0[r] *= corr; o1[r] *= corr; }
        m = mnew;
      }
      float ps = 0.f;
      #pragma unroll
      for (int r = 0; r < 16; ++r){ st0[r] = exp2f(st0[r] - m); ps += st0[r]; }
      if (do1)
        #pragma unroll
        for (int r = 0; r < 16; ++r){ st1[r] = exp2f(st1[r] - m); ps += st1[r]; }
      {
        int pa = __float_as_int(ps), pb = __float_as_int(ps);
        pl32(pa, pb);
        ps = __int_as_float(pa) + __int_as_float(pb);
      }
      lsum += ps;

      // ---- P^T B-frags: pk2 + permlane32_swap ----
      short8v pf[4];
      #define MAKE_PF(ST, BASE, OUT) { \
        int aa = pk2(ST[BASE+0], ST[BASE+1]); \
        int cc2 = pk2(ST[BASE+2], ST[BASE+3]); \
        int bb = pk2(ST[BASE+4], ST[BASE+5]); \
        int dd = pk2(ST[BASE+6], ST[BASE+7]); \
        pl32(aa, bb); pl32(cc2, dd); \
        int4 wi; wi.x = aa; wi.y = cc2; wi.z = bb; wi.w = dd; \
        OUT = *reinterpret_cast<short8v*>(&wi); }
      MAKE_PF(st0, 0, pf[0])
      MAKE_PF(st0, 8, pf[1])
      if (do1){
        MAKE_PF(st1, 0, pf[2])
        MAKE_PF(st1, 8, pf[3])
      }
      #undef MAKE_PF

      // ---- O^T += V^T * P^T ----
      #pragma unroll
      for (int s = 0; s < 2; ++s){
        const int byteA = bsel + ((l31 * 128 + s * 32 + lh * 16) ^ ((l31 & 7) << 4));
        const int byteB = bsel + (((32 + l31) * 128 + s * 32 + lh * 16) ^ ((l31 & 7) << 4));
        o0 = mfma32(*reinterpret_cast<const short8v*>(VsB + byteA), pf[s], o0);
        o1 = mfma32(*reinterpret_cast<const short8v*>(VsB + byteB), pf[s], o1);
      }
      if (do1){
        #pragma unroll
        for (int s = 2; s < 4; ++s){
          const int byteA = bsel + ((l31 * 128 + s * 32 + lh * 16) ^ ((l31 & 7) << 4));
          const int byteB = bsel + (((32 + l31) * 128 + s * 32 + lh * 16) ^ ((l31 & 7) << 4));
          o0 = mfma32(*reinterpret_cast<const short8v*>(VsB + byteA), pf[s], o0);
          o1 = mfma32(*reinterpret_cast<const short8v*>(VsB + byteB), pf[s], o1);
        }
      }
    }
    __syncthreads();   // drains stage(t+1) + releases buf t&1
  }
  #undef AT_STAGE

  const int prow = (b * PCB + g) * QB + wq * 32 + l31;
  unsigned short* Od = Opart + (size_t)prow * 64;
  #define WRITE_O(OO, DT) { \
    _Pragma("unroll") \
    for (int quad = 0; quad < 4; ++quad){ \
      short4v pkk; \
      _Pragma("unroll") \
      for (int r = 0; r < 4; ++r) pkk[r] = (short)f2bf(OO[quad * 4 + r]); \
      *reinterpret_cast<short4v*>(Od + DT * 32 + 8 * quad + 4 * lh) = pkk; } }
  WRITE_O(o0, 0)
  WRITE_O(o1, 1)
  #undef WRITE_O
  if (lane < 32){
    Mpart[prow] = m;
    Lpart[prow] = lsum;
  }
}

// ---------------- combine partials (QB=128, round-15 verbatim) ----------------
template<int CHUNK>
__global__ __launch_bounds__(256) void combine_kernel(
    const unsigned short* __restrict__ Opart, const float* __restrict__ Mpart,
    const float* __restrict__ Lpart, float* __restrict__ out){
  constexpr int QB  = 128;
  constexpr int GS  = CHUNK / QB;
  constexpr int NG  = SEQ / CHUNK;
  constexpr int PCB = GS * NG * (NG + 1) / 2;
  const int gid = blockIdx.x * 4 + (threadIdx.x >> 6);   // global row 0..16383
  const int d   = threadIdx.x & 63;
  const int b   = gid >> 12;
  const int q   = gid & (SEQ - 1);
  const int qj  = q >> 7;                                // 128-row q-block
  const int A   = qj / GS;
  const int nch = A + 1;
  const int p0  = b * PCB + GS * A * (A + 1) / 2 + (qj - A * GS) * (A + 1);
  const int ql  = q & (QB - 1);

  float M = -1e30f;
  for (int cc = 0; cc < nch; ++cc) M = fmaxf(M, Mpart[(p0 + cc) * QB + ql]);
  float L = 0.f, O = 0.f;
  for (int cc = 0; cc < nch; ++cc){
    const float s = exp2f(Mpart[(p0 + cc) * QB + ql] - M);
    L += s * Lpart[(p0 + cc) * QB + ql];
    const unsigned short ob = Opart[((size_t)(p0 + cc) * QB + ql) * 64 + d];
    O += s * __uint_as_float((unsigned)ob << 16);
  }
  out[(size_t)gid * 64 + d] = O / L;
}

extern "C" void kernel_launch(void* const* d_in, const int* in_sizes, int n_in,
                              void* d_out, int out_size, void* d_ws, size_t ws_size,
                              hipStream_t stream){
  const float* x  = (const float*)d_in[0];
  const float* Wq = (const float*)d_in[1];
  const float* Wk = (const float*)d_in[2];
  const float* Wv = (const float*)d_in[3];

  const size_t nqkv = (size_t)BATCH * SEQ * HS;
  unsigned short* Qb = (unsigned short*)d_ws;
  unsigned short* Kb = Qb + nqkv;
  unsigned short* Vt = Kb + nqkv;                     // [HS][BATCH*SEQ]
  unsigned short* Wpack = Vt + nqkv;                  // 196608 ushorts = 384 KB
  unsigned short* Opart = Wpack + (size_t)196608;

  pack32_kernel<<<96, 256, 0, stream>>>(Wq, Wk, Wv, Wpack);
  proj_mfma<<<(BATCH * SEQ) / 32, 128, 0, stream>>>(x, Wpack, Qb, Kb, Vt);

  constexpr int PCB512  = 4 * 8 * 9 / 2;      // 144
  constexpr int PCB1024 = 8 * 4 * 5 / 2;      // 80
  constexpr int PCB4096 = 32 * 1 * 2 / 2;     // 32
  const size_t base_bytes = (3 * nqkv + (size_t)196608) * sizeof(unsigned short);
  auto pbytes = [](int pcb){ return (size_t)BATCH * pcb * 128 * (64 * 2 + 8); };

  if (ws_size >= base_bytes + pbytes(PCB512)){
    float* Mpart = (float*)(Opart + (size_t)BATCH * PCB512 * 128 * 64);
    float* Lpart = Mpart + (size_t)BATCH * PCB512 * 128;
    attn_partial<512><<<BATCH * PCB512, 256, 0, stream>>>(Qb, Kb, Vt, Opart, Mpart, Lpart);
    combine_kernel<512><<<BATCH * SEQ / 4, 256, 0, stream>>>(Opart, Mpart, Lpart, (float*)d_out);
  } else if (ws_size >= base_bytes + pbytes(PCB1024)){
    float* Mpart = (float*)(Opart + (size_t)BATCH * PCB1024 * 128 * 64);
    float* Lpart = Mpart + (size_t)BATCH * PCB1024 * 128;
    attn_partial<1024><<<BATCH * PCB1024, 256, 0, stream>>>(Qb, Kb, Vt, Opart, Mpart, Lpart);
    combine_kernel<1024><<<BATCH * SEQ / 4, 256, 0, stream>>>(Opart, Mpart, Lpart, (float*)d_out);
  } else {
    float* Mpart = (float*)(Opart + (size_t)BATCH * PCB4096 * 128 * 64);
    float* Lpart = Mpart + (size_t)BATCH * PCB4096 * 128;
    attn_partial<4096><<<BATCH * PCB4096, 256, 0, stream>>>(Qb, Kb, Vt, Opart, Mpart, Lpart);
    combine_kernel<4096><<<BATCH * SEQ / 4, 256, 0, stream>>>(Opart, Mpart, Lpart, (float*)d_out);
  }
}